// Round 4
// baseline (605.939 us; speedup 1.0000x reference)
//
#include <hip/hip_runtime.h>
#include <math.h>

#define B_ 128
#define S_ 1024
#define D_ 512
#define H_ 512

typedef _Float16 f16x4 __attribute__((ext_vector_type(4)));
typedef _Float16 f16x8 __attribute__((ext_vector_type(8)));
typedef float    f32x4 __attribute__((ext_vector_type(4)));

typedef __attribute__((address_space(3))) uint32_t lds_u32_t;
typedef const __attribute__((address_space(1))) uint32_t glb_u32_t;

// async 16B/lane global->LDS DMA (lds dst = wave-uniform base + lane*16)
__device__ __forceinline__ void async_copy16(const void* gsrc, void* ldst) {
    __builtin_amdgcn_global_load_lds((glb_u32_t*)gsrc, (lds_u32_t*)ldst, 16, 0, 0);
}

// ---------------------------------------------------------------------------
__global__ void zero_k(float* __restrict__ p, int n) {
    int i = blockIdx.x * 256 + threadIdx.x;
    if (i < n) p[i] = 0.f;
}

// ---------------------------------------------------------------------------
__device__ inline f16x4 cvt4(float4 v) {
    f16x4 r;
    r[0] = (_Float16)v.x; r[1] = (_Float16)v.y;
    r[2] = (_Float16)v.z; r[3] = (_Float16)v.w;
    return r;
}

// W_ctx fp32 -> fp16 (0.5 MB, L2-resident thereafter)
__global__ __launch_bounds__(256) void w16_k(const float* __restrict__ W,
                                             _Float16* __restrict__ out) {
    int i = blockIdx.x * 256 + threadIdx.x;   // over H*D/4
    float4 v = ((const float4*)W)[i];
    *(f16x4*)(out + 4 * (size_t)i) = cvt4(v);
}

// ---------------------------------------------------------------------------
// out[b,h] = dot(X[b,:], W[h,:]) + bias[h]
__global__ __launch_bounds__(256) void linear_k(const float* __restrict__ X,
                                                const float* __restrict__ W,
                                                const float* __restrict__ bias,
                                                float* __restrict__ out) {
    int idx = blockIdx.x * 256 + threadIdx.x;
    int b = idx >> 9;
    int h = idx & 511;
    const float4* x = (const float4*)(X + (size_t)b * D_);
    const float4* w = (const float4*)(W + (size_t)h * D_);
    float s = 0.f;
#pragma unroll 8
    for (int k = 0; k < D_ / 4; ++k) {
        float4 xv = x[k], wv = w[k];
        s = fmaf(xv.x, wv.x, s);
        s = fmaf(xv.y, wv.y, s);
        s = fmaf(xv.z, wv.z, s);
        s = fmaf(xv.w, wv.w, s);
    }
    out[idx] = s + bias[h];
}

// fast tanh: 1 - 2/(e^{2x}+1)
__device__ inline float fast_tanh(float x) {
    float e = __expf(2.f * x);
    return 1.f - 2.f / (e + 1.f);
}

// ---------------------------------------------------------------------------
// Score GEMM: 128(h)x128(s) tile, fp16 MFMA.
//  - B (ctx) fp32 staged via global_load_lds, double-buffered, XOR-swizzled
//  - A (W16) fp16 fragment-loaded direct from global (L2-hot, 0.5 MB)
//  - XCD-aware block swizzle: 4 h-siblings of one ctx panel on one XCD
// Epilogue: att[b,s] += sum_h V[h]*tanh(inp[b,h]+b_ctx[h]+score) (atomicAdd)
__global__ __launch_bounds__(256) void score_mfma(const float* __restrict__ ctx,
                                                  const _Float16* __restrict__ W16,
                                                  const float* __restrict__ bc,
                                                  const float* __restrict__ Vv,
                                                  const float* __restrict__ inp,
                                                  float* __restrict__ att) {
    // B tile: 128 rows(s) x 32 floats(k), stored as 16 chunks of 8 rows;
    // within a row, 16B-group g stored at slot g^(row&7)  -> conflict-free reads
    __shared__ __align__(16) float Bs[2][4096];   // 2 x 16 KB
    __shared__ float red[8][128];

    const int tid = threadIdx.x;
    // XCD swizzle: f = xcd + 8*(4*gi + hb); hw maps block f -> XCD f%8.
    // Siblings hb=0..3 of group g are consecutive on the same XCD.
    const int f   = blockIdx.x;
    const int xcd = f & 7;
    const int hb  = (f >> 3) & 3;
    const int g   = (f >> 5) * 8 + xcd;      // 0..1023 = (s-blk, b)
    const int h0  = hb * 128;
    const int s0  = (g & 7) * 128;
    const int b   = g >> 3;

    const int wave = tid >> 6;
    const int lane = tid & 63;
    const int wm = wave >> 1, wn = wave & 1;   // 2x2 wave grid (h x s)
    const int l15 = lane & 15, quad = lane >> 4;

    // DMA source: lane covers row lrow of an 8-row chunk, stores slot lslot,
    // which must hold logical kgroup lslot^lrow.
    const int lrow  = lane >> 3;
    const int lslot = lane & 7;
    const int gk    = lslot ^ lrow;
    const float* bsrc = ctx + ((size_t)b * S_ + s0 + 32 * wave + lrow) * D_ + gk * 4;

    f32x4 acc[4][4];
#pragma unroll
    for (int mi = 0; mi < 4; ++mi)
#pragma unroll
        for (int ni = 0; ni < 4; ++ni) acc[mi][ni] = (f32x4){0.f, 0.f, 0.f, 0.f};

    const _Float16* Afrag = W16 + (size_t)(h0 + wm * 64 + l15) * D_ + quad * 8;

    // prologue: DMA tile 0 into buf 0, A frags for step 0
#pragma unroll
    for (int it = 0; it < 4; ++it)
        async_copy16(bsrc + (size_t)it * 8 * D_, &Bs[0][wave * 1024 + it * 256]);
    f16x8 af[4], afn[4];
#pragma unroll
    for (int mi = 0; mi < 4; ++mi)
        af[mi] = *(const f16x8*)(Afrag + (size_t)mi * 16 * D_);
    __syncthreads();   // drains DMA (compiler emits vmcnt(0))

    for (int ks = 0; ks < 16; ++ks) {
        const int buf = ks & 1;
        if (ks < 15) {
            const float* sb = bsrc + (ks + 1) * 32;
#pragma unroll
            for (int it = 0; it < 4; ++it)
                async_copy16(sb + (size_t)it * 8 * D_, &Bs[buf ^ 1][wave * 1024 + it * 256]);
#pragma unroll
            for (int mi = 0; mi < 4; ++mi)
                afn[mi] = *(const f16x8*)(Afrag + (size_t)mi * 16 * D_ + (ks + 1) * 32);
        }
        // B fragments: lane n=l15, k=quad*8+j ; row r = wn*64+ni*16+l15
        f16x8 bf[4];
#pragma unroll
        for (int ni = 0; ni < 4; ++ni) {
            const int r = wn * 64 + ni * 16 + l15;
            const int rr = r & 7;
            const int base = (r >> 3) * 256 + rr * 32;
            const int s1 = (2 * quad) ^ rr;
            f32x4 u = *(const f32x4*)&Bs[buf][base + s1 * 4];
            f32x4 v = *(const f32x4*)&Bs[buf][base + (s1 ^ 1) * 4];
            f16x8 h;
            h[0] = (_Float16)u[0]; h[1] = (_Float16)u[1];
            h[2] = (_Float16)u[2]; h[3] = (_Float16)u[3];
            h[4] = (_Float16)v[0]; h[5] = (_Float16)v[1];
            h[6] = (_Float16)v[2]; h[7] = (_Float16)v[3];
            bf[ni] = h;
        }
#pragma unroll
        for (int mi = 0; mi < 4; ++mi)
#pragma unroll
            for (int ni = 0; ni < 4; ++ni)
                acc[mi][ni] = __builtin_amdgcn_mfma_f32_16x16x32_f16(af[mi], bf[ni], acc[mi][ni], 0, 0, 0);
#pragma unroll
        for (int mi = 0; mi < 4; ++mi) af[mi] = afn[mi];
        __syncthreads();   // releases buf for DMA overwrite; drains next DMA
    }

    // epilogue: C/D layout col=l15 (s), row=quad*4+reg (h)
    float p[4] = {0.f, 0.f, 0.f, 0.f};
#pragma unroll
    for (int mi = 0; mi < 4; ++mi) {
#pragma unroll
        for (int r = 0; r < 4; ++r) {
            const int h = h0 + wm * 64 + mi * 16 + quad * 4 + r;
            const float c  = inp[(size_t)b * H_ + h] + bc[h];
            const float vh = Vv[h];
#pragma unroll
            for (int ni = 0; ni < 4; ++ni)
                p[ni] = fmaf(vh, fast_tanh(c + acc[mi][ni][r]), p[ni]);
        }
    }
    const int cid = wm * 4 + quad;
#pragma unroll
    for (int ni = 0; ni < 4; ++ni)
        red[cid][wn * 64 + ni * 16 + l15] = p[ni];
    __syncthreads();
    if (tid < 128) {
        float s = 0.f;
#pragma unroll
        for (int gg = 0; gg < 8; ++gg) s += red[gg][tid];
        atomicAdd(att + (size_t)b * S_ + s0 + tid, s);
    }
}

// ---------------------------------------------------------------------------
__global__ __launch_bounds__(256) void softmax_k(const float* __restrict__ att,
                                                 const int* __restrict__ mask,
                                                 float* __restrict__ alpha) {
    const int b = blockIdx.x;
    const int t = threadIdx.x;
    __shared__ float sm[256];
    float v[4];
    float mx = -INFINITY;
#pragma unroll
    for (int i = 0; i < 4; ++i) {
        int s = t + i * 256;
        float a = att[(size_t)b * S_ + s];
        int mk = mask[(size_t)b * S_ + s];
        v[i] = mk ? -INFINITY : a;
        mx = fmaxf(mx, v[i]);
    }
    sm[t] = mx;
    __syncthreads();
    for (int off = 128; off > 0; off >>= 1) {
        if (t < off) sm[t] = fmaxf(sm[t], sm[t + off]);
        __syncthreads();
    }
    mx = sm[0];
    __syncthreads();
    float e[4];
    float sum = 0.f;
#pragma unroll
    for (int i = 0; i < 4; ++i) {
        e[i] = expf(v[i] - mx);
        sum += e[i];
    }
    sm[t] = sum;
    __syncthreads();
    for (int off = 128; off > 0; off >>= 1) {
        if (t < off) sm[t] += sm[t + off];
        __syncthreads();
    }
    float inv = 1.f / sm[0];
#pragma unroll
    for (int i = 0; i < 4; ++i) alpha[(size_t)b * S_ + t + i * 256] = e[i] * inv;
}

// ---------------------------------------------------------------------------
__global__ __launch_bounds__(256) void cbar_k(const float* __restrict__ ctx,
                                              const float* __restrict__ alpha,
                                              float* __restrict__ cbar) {
    const int b = blockIdx.y;
    const int s0 = blockIdx.x * 128;
    const int t = threadIdx.x;
    const int c4 = t & 127;
    const int sh = t >> 7;
    __shared__ float al[128];
    __shared__ float4 red[128];
    if (t < 128) al[t] = alpha[(size_t)b * S_ + s0 + t];
    __syncthreads();
    const float4* base = (const float4*)(ctx + ((size_t)b * S_ + s0) * D_);
    float4 c = {0.f, 0.f, 0.f, 0.f};
#pragma unroll 4
    for (int s = sh; s < 128; s += 2) {
        float a = al[s];
        float4 x = base[(size_t)s * (D_ / 4) + c4];
        c.x = fmaf(a, x.x, c.x);
        c.y = fmaf(a, x.y, c.y);
        c.z = fmaf(a, x.z, c.z);
        c.w = fmaf(a, x.w, c.w);
    }
    if (sh == 1) red[c4] = c;
    __syncthreads();
    if (sh == 0) {
        float4 o = red[c4];
        float* dst = cbar + (size_t)b * D_ + c4 * 4;
        atomicAdd(dst + 0, c.x + o.x);
        atomicAdd(dst + 1, c.y + o.y);
        atomicAdd(dst + 2, c.z + o.z);
        atomicAdd(dst + 3, c.w + o.w);
    }
}

// ---------------------------------------------------------------------------
extern "C" void kernel_launch(void* const* d_in, const int* in_sizes, int n_in,
                              void* d_out, int out_size, void* d_ws, size_t ws_size,
                              hipStream_t stream) {
    const float* input = (const float*)d_in[0];
    const float* ctx   = (const float*)d_in[1];
    const int*   mask  = (const int*)d_in[2];
    const float* W_in  = (const float*)d_in[3];
    const float* b_in  = (const float*)d_in[4];
    const float* W_ctx = (const float*)d_in[5];
    const float* b_ctx = (const float*)d_in[6];
    const float* V     = (const float*)d_in[7];

    float* hidden = (float*)d_out;
    float* alpha  = (float*)d_out + B_ * H_;

    float* inp  = (float*)d_ws;                    // B*H fp32
    float* att  = inp + B_ * H_;                   // B*S
    float* cbar = att + B_ * S_;                   // B*D
    _Float16* W16 = (_Float16*)(cbar + B_ * D_);   // H*D fp16

    int nz = B_ * S_ + B_ * D_;
    zero_k<<<(nz + 255) / 256, 256, 0, stream>>>(att, nz);

    w16_k<<<(H_ * D_ / 4) / 256, 256, 0, stream>>>(W_ctx, W16);

    linear_k<<<(B_ * H_) / 256, 256, 0, stream>>>(input, W_in, b_in, inp);

    score_mfma<<<4096, 256, 0, stream>>>(ctx, W16, b_ctx, V, inp, att);

    softmax_k<<<B_, 256, 0, stream>>>(att, mask, alpha);

    dim3 g4(S_ / 128, B_);
    cbar_k<<<g4, 256, 0, stream>>>(ctx, alpha, cbar);

    linear_k<<<(B_ * H_) / 256, 256, 0, stream>>>(cbar, W_ctx, b_ctx, hidden);
}